// Round 1
// baseline (466.971 us; speedup 1.0000x reference)
//
#include <hip/hip_runtime.h>
#include <hip/hip_bf16.h>

// LVQ: out[n] = classes[argmin_k ||x_n - c_k||^2]
// N=65536, D=512, K=1024, classes int32.
//
// score[n][k] = csq[k] - 2 * x_n . c_k   (x_sq dropped: row-constant)
// cross via 3-pass bf16-split MFMA (xh*ch + xh*cl + xl*ch), fp32 accum.
// Fused argmin epilogue -> packed (key,col) atomicMin merge in d_ws.

#define N_ROWS 65536
#define DIM    512
#define K_CB   1024

typedef short bf16x8 __attribute__((ext_vector_type(8)));
typedef float f32x4  __attribute__((ext_vector_type(4)));

__device__ __forceinline__ unsigned short f2bf_rn(float f) {
    unsigned u = __float_as_uint(f);
    unsigned r = (u + 0x7FFFu + ((u >> 16) & 1u)) >> 16;
    return (unsigned short)r;
}
__device__ __forceinline__ float bf2f(unsigned short h) {
    return __uint_as_float(((unsigned)h) << 16);
}

// ---------------- init: packed per-row (min,argmin) to +inf ----------------
__global__ void init_kernel(unsigned long long* __restrict__ packed) {
    int n = blockIdx.x * 256 + threadIdx.x;
    if (n < N_ROWS) packed[n] = ~0ull;
}

// ---------------- csq[k] = sum_d C[k][d]^2 (fp32) ----------------
__global__ void csq_kernel(const float* __restrict__ C, float* __restrict__ csq) {
    int wid  = (blockIdx.x * blockDim.x + threadIdx.x) >> 6;   // one wave per k
    int lane = threadIdx.x & 63;
    const float4* p = (const float4*)(C + (size_t)wid * DIM);
    float4 a = p[lane * 2];
    float4 b = p[lane * 2 + 1];
    float s = a.x*a.x + a.y*a.y + a.z*a.z + a.w*a.w
            + b.x*b.x + b.y*b.y + b.z*b.z + b.w*b.w;
    #pragma unroll
    for (int m = 1; m < 64; m <<= 1) s += __shfl_xor(s, m, 64);
    if (lane == 0) csq[wid] = s;
}

// ---------------- staging: fp32 global tile -> bf16 hi/lo LDS (swizzled) ----
// src points at element [tile_row0][d0]; row stride DIM floats.
// LDS layout: H[row*64 + (g ^ (row&7))*8 + (c&7)] where g = c>>3, c = column 0..63.
__device__ __forceinline__ void stage_tile(const float* __restrict__ src,
                                           unsigned short* __restrict__ Hh,
                                           unsigned short* __restrict__ Hl,
                                           int t) {
    int rsub = t >> 4;            // 0..15
    int f4i  = t & 15;            // which float4 in the row (0..15)
    int g    = f4i >> 1;          // 16B group 0..7
    int off  = (f4i & 1) * 4;     // offset within group
    #pragma unroll
    for (int p = 0; p < 8; p++) {
        int row = p * 16 + rsub;
        float4 v = *(const float4*)(src + (size_t)row * DIM + f4i * 4);
        ushort4 h, l;
        {
            float f;
            f = v.x; h.x = f2bf_rn(f); l.x = f2bf_rn(f - bf2f(h.x));
            f = v.y; h.y = f2bf_rn(f); l.y = f2bf_rn(f - bf2f(h.y));
            f = v.z; h.z = f2bf_rn(f); l.z = f2bf_rn(f - bf2f(h.z));
            f = v.w; h.w = f2bf_rn(f); l.w = f2bf_rn(f - bf2f(h.w));
        }
        int sg  = g ^ (row & 7);
        int idx = row * 64 + sg * 8 + off;
        *(ushort4*)(Hh + idx) = h;
        *(ushort4*)(Hl + idx) = l;
    }
}

// ---------------- fused GEMM + argmin ----------------
// Tiles: BM=128 rows x BN=128 codebook cols, BK=64. 256 threads = 4 waves (2x2),
// wave tile 64x64 = 4x4 fragments of 16x16, K-depth 32 per MFMA.
__global__ __launch_bounds__(256, 2)
void gemm_argmin(const float* __restrict__ X, const float* __restrict__ C,
                 const float* __restrict__ csq,
                 unsigned long long* __restrict__ packed) {
    __shared__ unsigned short Ah[128 * 64];
    __shared__ unsigned short Al[128 * 64];
    __shared__ unsigned short Bh[128 * 64];
    __shared__ unsigned short Bl[128 * 64];

    // XCD-aware mapping: the 8 col-tiles of one row-tile land on one XCD
    // (blockIdx round-robins XCDs %8) -> X tile fetched from HBM ~once.
    int b = blockIdx.x;
    int x = b & 7;
    int m8 = b >> 3;                  // 0..511
    int rowtile = x * 64 + (m8 >> 3); // 0..511
    int coltile = m8 & 7;             // 0..7
    int n0 = rowtile * 128;
    int k0 = coltile * 128;

    int t    = threadIdx.x;
    int w    = t >> 6;
    int lane = t & 63;
    int wr   = w >> 1, wc = w & 1;
    int rbase = wr * 64, cbase = wc * 64;
    int lrow = lane & 15;
    int lk   = lane >> 4;             // 0..3

    f32x4 acc[4][4];
    #pragma unroll
    for (int i = 0; i < 4; i++)
        #pragma unroll
        for (int j = 0; j < 4; j++)
            acc[i][j] = (f32x4){0.f, 0.f, 0.f, 0.f};

    for (int d0 = 0; d0 < DIM; d0 += 64) {
        stage_tile(X + (size_t)n0 * DIM + d0, Ah, Al, t);
        stage_tile(C + (size_t)k0 * DIM + d0, Bh, Bl, t);
        __syncthreads();

        #pragma unroll
        for (int kk = 0; kk < 2; kk++) {
            int gidx = kk * 4 + lk;   // 16B group index along k
            bf16x8 ah[4], al[4], bh[4], bl[4];
            #pragma unroll
            for (int m = 0; m < 4; m++) {
                int row = rbase + m * 16 + lrow;
                int sg  = gidx ^ (row & 7);
                ah[m] = *(const bf16x8*)&Ah[row * 64 + sg * 8];
                al[m] = *(const bf16x8*)&Al[row * 64 + sg * 8];
            }
            #pragma unroll
            for (int n = 0; n < 4; n++) {
                int col = cbase + n * 16 + lrow;
                int sg  = gidx ^ (col & 7);
                bh[n] = *(const bf16x8*)&Bh[col * 64 + sg * 8];
                bl[n] = *(const bf16x8*)&Bl[col * 64 + sg * 8];
            }
            #pragma unroll
            for (int m = 0; m < 4; m++)
                #pragma unroll
                for (int n = 0; n < 4; n++) {
                    acc[m][n] = __builtin_amdgcn_mfma_f32_16x16x32_bf16(ah[m], bh[n], acc[m][n], 0, 0, 0);
                    acc[m][n] = __builtin_amdgcn_mfma_f32_16x16x32_bf16(ah[m], bl[n], acc[m][n], 0, 0, 0);
                    acc[m][n] = __builtin_amdgcn_mfma_f32_16x16x32_bf16(al[m], bh[n], acc[m][n], 0, 0, 0);
                }
        }
        __syncthreads();
    }

    // Epilogue: score = csq[col] - 2*cross; per-row packed-min, atomic merge.
    float cs[4];
    #pragma unroll
    for (int n = 0; n < 4; n++) cs[n] = csq[k0 + cbase + n * 16 + lrow];

    #pragma unroll
    for (int m = 0; m < 4; m++) {
        #pragma unroll
        for (int r = 0; r < 4; r++) {
            unsigned long long best = ~0ull;
            #pragma unroll
            for (int n = 0; n < 4; n++) {
                float s = cs[n] - 2.0f * acc[m][n][r];
                unsigned kb  = __float_as_uint(s);
                unsigned key = kb ^ (unsigned)(((int)kb >> 31) | 0x80000000);
                unsigned col = (unsigned)(k0 + cbase + n * 16 + lrow);
                unsigned long long pk = (((unsigned long long)key) << 32) | col;
                best = pk < best ? pk : best;
            }
            // butterfly across the 16 lanes holding this row (low 4 lane bits)
            #pragma unroll
            for (int mask = 1; mask <= 8; mask <<= 1) {
                unsigned hi = __shfl_xor((unsigned)(best >> 32), mask, 64);
                unsigned lo = __shfl_xor((unsigned)(best & 0xFFFFFFFFu), mask, 64);
                unsigned long long other = (((unsigned long long)hi) << 32) | lo;
                best = other < best ? other : best;
            }
            if (lrow == 0) {
                int grow = n0 + rbase + m * 16 + lk * 4 + r;
                atomicMin(&packed[grow], best);
            }
        }
    }
}

// ---------------- winner -> class ----------------
__global__ void map_kernel(const unsigned long long* __restrict__ packed,
                           const int* __restrict__ classes,
                           int* __restrict__ out) {
    int n = blockIdx.x * 256 + threadIdx.x;
    if (n < N_ROWS) {
        unsigned col = (unsigned)(packed[n] & 0xFFFFFFFFull);
        out[n] = classes[col];
    }
}

extern "C" void kernel_launch(void* const* d_in, const int* in_sizes, int n_in,
                              void* d_out, int out_size, void* d_ws, size_t ws_size,
                              hipStream_t stream) {
    const float* X       = (const float*)d_in[0];
    const float* C       = (const float*)d_in[1];
    const int*   classes = (const int*)d_in[2];
    int*         out     = (int*)d_out;

    unsigned long long* packed = (unsigned long long*)d_ws;
    float* csq = (float*)((char*)d_ws + (size_t)N_ROWS * 8);

    init_kernel<<<N_ROWS / 256, 256, 0, stream>>>(packed);
    csq_kernel<<<K_CB / 4, 256, 0, stream>>>(C, csq);
    gemm_argmin<<<(N_ROWS / 128) * (K_CB / 128), 256, 0, stream>>>(X, C, csq, packed);
    map_kernel<<<N_ROWS / 256, 256, 0, stream>>>(packed, classes, out);
}

// Round 2
// 282.454 us; speedup vs baseline: 1.6533x; 1.6533x over previous
//
#include <hip/hip_runtime.h>
#include <hip/hip_bf16.h>

// LVQ: out[n] = classes[argmin_k ||x_n - c_k||^2]
// N=65536, D=512, K=1024, classes int32.
//
// score[n][k] = csq[k] - 2 * x_n . c_k   (x_sq dropped: row-constant)
// cross via 3-pass bf16-split MFMA (xh*ch + xh*cl + xl*ch), fp32 accum.
// Round 2: pre-split X/C into bf16 hi/lo arrays in d_ws (one-shot, memory-
// bound), GEMM stages via global_load_lds width=16 with source-side XOR
// swizzle (linear LDS dest). Fallback to in-kernel conversion if ws small.

#define N_ROWS 65536
#define DIM    512
#define K_CB   1024

typedef short bf16x8 __attribute__((ext_vector_type(8)));
typedef float f32x4  __attribute__((ext_vector_type(4)));

__device__ __forceinline__ unsigned short f2bf_rn(float f) {
    unsigned u = __float_as_uint(f);
    unsigned r = (u + 0x7FFFu + ((u >> 16) & 1u)) >> 16;
    return (unsigned short)r;
}
__device__ __forceinline__ float bf2f(unsigned short h) {
    return __uint_as_float(((unsigned)h) << 16);
}

__device__ __forceinline__ void gload16(const void* g, void* l) {
    __builtin_amdgcn_global_load_lds(
        (const __attribute__((address_space(1))) unsigned int*)g,
        (__attribute__((address_space(3))) unsigned int*)l, 16, 0, 0);
}

// ---------------- init: packed per-row (min,argmin) to +inf ----------------
__global__ void init_kernel(unsigned long long* __restrict__ packed) {
    int n = blockIdx.x * 256 + threadIdx.x;
    if (n < N_ROWS) packed[n] = ~0ull;
}

// ---------------- csq[k] = sum_d C[k][d]^2 (fp32) ----------------
__global__ void csq_kernel(const float* __restrict__ C, float* __restrict__ csq) {
    int wid  = (blockIdx.x * blockDim.x + threadIdx.x) >> 6;   // one wave per k
    int lane = threadIdx.x & 63;
    const float4* p = (const float4*)(C + (size_t)wid * DIM);
    float4 a = p[lane * 2];
    float4 b = p[lane * 2 + 1];
    float s = a.x*a.x + a.y*a.y + a.z*a.z + a.w*a.w
            + b.x*b.x + b.y*b.y + b.z*b.z + b.w*b.w;
    #pragma unroll
    for (int m = 1; m < 64; m <<= 1) s += __shfl_xor(s, m, 64);
    if (lane == 0) csq[wid] = s;
}

// ---------------- one-shot fp32 -> bf16 hi/lo split ----------------
__global__ void split_kernel(const float* __restrict__ src,
                             unsigned short* __restrict__ h,
                             unsigned short* __restrict__ l, int n4) {
    int stride = gridDim.x * 256;
    for (int i = blockIdx.x * 256 + threadIdx.x; i < n4; i += stride) {
        float4 v = ((const float4*)src)[i];
        ushort4 hh, ll;
        float f;
        f = v.x; hh.x = f2bf_rn(f); ll.x = f2bf_rn(f - bf2f(hh.x));
        f = v.y; hh.y = f2bf_rn(f); ll.y = f2bf_rn(f - bf2f(hh.y));
        f = v.z; hh.z = f2bf_rn(f); ll.z = f2bf_rn(f - bf2f(hh.z));
        f = v.w; hh.w = f2bf_rn(f); ll.w = f2bf_rn(f - bf2f(hh.w));
        ((ushort4*)h)[i] = hh;
        ((ushort4*)l)[i] = ll;
    }
}

// ---------------- fused GEMM + argmin (fast path: pre-split inputs) --------
// Tiles: BM=128 rows x BN=128 codebook cols, BK=64. 256 threads = 4 waves
// (2x2), wave tile 64x64 = 4x4 fragments of 16x16, K-depth 32 per MFMA.
// LDS layout per tile: [row][sg*8+off] with sg = g ^ (row&7) (16B-group XOR
// swizzle). global_load_lds writes linearly (lane*16B); the swizzle is
// applied on the per-lane GLOBAL source address (involution), reads use the
// same XOR.
__global__ __launch_bounds__(256, 2)
void gemm_argmin(const unsigned short* __restrict__ Xh,
                 const unsigned short* __restrict__ Xl,
                 const unsigned short* __restrict__ Ch,
                 const unsigned short* __restrict__ Cl,
                 const float* __restrict__ csq,
                 unsigned long long* __restrict__ packed) {
    __shared__ unsigned short AhL[128 * 64];
    __shared__ unsigned short AlL[128 * 64];
    __shared__ unsigned short BhL[128 * 64];
    __shared__ unsigned short BlL[128 * 64];

    // XCD-aware mapping: 8 col-tiles of one row-tile run consecutively on
    // one XCD -> X tile L2-resident across them; Ch/Cl (2 MB) L2-resident.
    int b = blockIdx.x;
    int x = b & 7;
    int m8 = b >> 3;                  // 0..511
    int rowtile = x * 64 + (m8 >> 3); // 0..511
    int coltile = m8 & 7;             // 0..7
    int n0 = rowtile * 128;
    int k0 = coltile * 128;

    int t    = threadIdx.x;
    int w    = t >> 6;
    int lane = t & 63;
    int wr   = w >> 1, wc = w & 1;
    int rbase = wr * 64, cbase = wc * 64;
    int lrow = lane & 15;
    int lk   = lane >> 4;             // 0..3

    f32x4 acc[4][4];
    #pragma unroll
    for (int i = 0; i < 4; i++)
        #pragma unroll
        for (int j = 0; j < 4; j++)
            acc[i][j] = (f32x4){0.f, 0.f, 0.f, 0.f};

    for (int d0 = 0; d0 < DIM; d0 += 64) {
        // stage: wave w stages rows [w*32, w*32+32) of all 4 tiles.
        // chunk = 8 rows x 64 cols = 1 KB = one wave-wide gload16.
        #pragma unroll
        for (int i = 0; i < 4; i++) {
            int row0 = w * 32 + i * 8;
            int row  = row0 + (lane >> 3);
            int sg   = lane & 7;
            int gg   = sg ^ (row & 7);            // source 16B-group (involution)
            size_t goffA = (size_t)(n0 + row) * DIM + d0 + gg * 8;
            size_t goffB = (size_t)(k0 + row) * DIM + d0 + gg * 8;
            gload16(Xh + goffA, AhL + row0 * 64);
            gload16(Xl + goffA, AlL + row0 * 64);
            gload16(Ch + goffB, BhL + row0 * 64);
            gload16(Cl + goffB, BlL + row0 * 64);
        }
        __syncthreads();

        #pragma unroll
        for (int kk = 0; kk < 2; kk++) {
            int gidx = kk * 4 + lk;   // 16B group index along k
            bf16x8 ah[4], al[4], bh[4], bl[4];
            #pragma unroll
            for (int m = 0; m < 4; m++) {
                int row = rbase + m * 16 + lrow;
                int sg  = gidx ^ (row & 7);
                ah[m] = *(const bf16x8*)&AhL[row * 64 + sg * 8];
                al[m] = *(const bf16x8*)&AlL[row * 64 + sg * 8];
            }
            #pragma unroll
            for (int n = 0; n < 4; n++) {
                int col = cbase + n * 16 + lrow;
                int sg  = gidx ^ (col & 7);
                bh[n] = *(const bf16x8*)&BhL[col * 64 + sg * 8];
                bl[n] = *(const bf16x8*)&BlL[col * 64 + sg * 8];
            }
            #pragma unroll
            for (int m = 0; m < 4; m++)
                #pragma unroll
                for (int n = 0; n < 4; n++) {
                    acc[m][n] = __builtin_amdgcn_mfma_f32_16x16x32_bf16(ah[m], bh[n], acc[m][n], 0, 0, 0);
                    acc[m][n] = __builtin_amdgcn_mfma_f32_16x16x32_bf16(ah[m], bl[n], acc[m][n], 0, 0, 0);
                    acc[m][n] = __builtin_amdgcn_mfma_f32_16x16x32_bf16(al[m], bh[n], acc[m][n], 0, 0, 0);
                }
        }
        __syncthreads();
    }

    // Epilogue: score = csq[col] - 2*cross; per-row packed-min, atomic merge.
    float cs[4];
    #pragma unroll
    for (int n = 0; n < 4; n++) cs[n] = csq[k0 + cbase + n * 16 + lrow];

    #pragma unroll
    for (int m = 0; m < 4; m++) {
        #pragma unroll
        for (int r = 0; r < 4; r++) {
            unsigned long long best = ~0ull;
            #pragma unroll
            for (int n = 0; n < 4; n++) {
                float s = cs[n] - 2.0f * acc[m][n][r];
                unsigned kb  = __float_as_uint(s);
                unsigned key = kb ^ (unsigned)(((int)kb >> 31) | 0x80000000);
                unsigned col = (unsigned)(k0 + cbase + n * 16 + lrow);
                unsigned long long pk = (((unsigned long long)key) << 32) | col;
                best = pk < best ? pk : best;
            }
            #pragma unroll
            for (int mask = 1; mask <= 8; mask <<= 1) {
                unsigned hi = __shfl_xor((unsigned)(best >> 32), mask, 64);
                unsigned lo = __shfl_xor((unsigned)(best & 0xFFFFFFFFu), mask, 64);
                unsigned long long other = (((unsigned long long)hi) << 32) | lo;
                best = other < best ? other : best;
            }
            if (lrow == 0) {
                int grow = n0 + rbase + m * 16 + lk * 4 + r;
                atomicMin(&packed[grow], best);
            }
        }
    }
}

// ---------------- fallback GEMM (in-kernel conversion, round-1 path) -------
__device__ __forceinline__ void stage_tile_fb(const float* __restrict__ src,
                                              unsigned short* __restrict__ Hh,
                                              unsigned short* __restrict__ Hl,
                                              int t) {
    int rsub = t >> 4;
    int f4i  = t & 15;
    int g    = f4i >> 1;
    int off  = (f4i & 1) * 4;
    #pragma unroll
    for (int p = 0; p < 8; p++) {
        int row = p * 16 + rsub;
        float4 v = *(const float4*)(src + (size_t)row * DIM + f4i * 4);
        ushort4 h, l;
        float f;
        f = v.x; h.x = f2bf_rn(f); l.x = f2bf_rn(f - bf2f(h.x));
        f = v.y; h.y = f2bf_rn(f); l.y = f2bf_rn(f - bf2f(h.y));
        f = v.z; h.z = f2bf_rn(f); l.z = f2bf_rn(f - bf2f(h.z));
        f = v.w; h.w = f2bf_rn(f); l.w = f2bf_rn(f - bf2f(h.w));
        int sg  = g ^ (row & 7);
        int idx = row * 64 + sg * 8 + off;
        *(ushort4*)(Hh + idx) = h;
        *(ushort4*)(Hl + idx) = l;
    }
}

__global__ __launch_bounds__(256, 2)
void gemm_argmin_fb(const float* __restrict__ X, const float* __restrict__ C,
                    const float* __restrict__ csq,
                    unsigned long long* __restrict__ packed) {
    __shared__ unsigned short AhL[128 * 64];
    __shared__ unsigned short AlL[128 * 64];
    __shared__ unsigned short BhL[128 * 64];
    __shared__ unsigned short BlL[128 * 64];

    int b = blockIdx.x;
    int x = b & 7;
    int m8 = b >> 3;
    int rowtile = x * 64 + (m8 >> 3);
    int coltile = m8 & 7;
    int n0 = rowtile * 128;
    int k0 = coltile * 128;

    int t    = threadIdx.x;
    int w    = t >> 6;
    int lane = t & 63;
    int wr   = w >> 1, wc = w & 1;
    int rbase = wr * 64, cbase = wc * 64;
    int lrow = lane & 15;
    int lk   = lane >> 4;

    f32x4 acc[4][4];
    #pragma unroll
    for (int i = 0; i < 4; i++)
        #pragma unroll
        for (int j = 0; j < 4; j++)
            acc[i][j] = (f32x4){0.f, 0.f, 0.f, 0.f};

    for (int d0 = 0; d0 < DIM; d0 += 64) {
        stage_tile_fb(X + (size_t)n0 * DIM + d0, AhL, AlL, t);
        stage_tile_fb(C + (size_t)k0 * DIM + d0, BhL, BlL, t);
        __syncthreads();

        #pragma unroll
        for (int kk = 0; kk < 2; kk++) {
            int gidx = kk * 4 + lk;
            bf16x8 ah[4], al[4], bh[4], bl[4];
            #pragma unroll
            for (int m = 0; m < 4; m++) {
                int row = rbase + m * 16 + lrow;
                int sg  = gidx ^ (row & 7);
                ah[m] = *(const bf16x8*)&AhL[row * 64 + sg * 8];
                al[m] = *(const bf16x8*)&AlL[row * 64 + sg * 8];
            }
            #pragma unroll
            for (int n = 0; n < 4; n++) {
                int col = cbase + n * 16 + lrow;
                int sg  = gidx ^ (col & 7);
                bh[n] = *(const bf16x8*)&BhL[col * 64 + sg * 8];
                bl[n] = *(const bf16x8*)&BlL[col * 64 + sg * 8];
            }
            #pragma unroll
            for (int m = 0; m < 4; m++)
                #pragma unroll
                for (int n = 0; n < 4; n++) {
                    acc[m][n] = __builtin_amdgcn_mfma_f32_16x16x32_bf16(ah[m], bh[n], acc[m][n], 0, 0, 0);
                    acc[m][n] = __builtin_amdgcn_mfma_f32_16x16x32_bf16(ah[m], bl[n], acc[m][n], 0, 0, 0);
                    acc[m][n] = __builtin_amdgcn_mfma_f32_16x16x32_bf16(al[m], bh[n], acc[m][n], 0, 0, 0);
                }
        }
        __syncthreads();
    }

    float cs[4];
    #pragma unroll
    for (int n = 0; n < 4; n++) cs[n] = csq[k0 + cbase + n * 16 + lrow];

    #pragma unroll
    for (int m = 0; m < 4; m++) {
        #pragma unroll
        for (int r = 0; r < 4; r++) {
            unsigned long long best = ~0ull;
            #pragma unroll
            for (int n = 0; n < 4; n++) {
                float s = cs[n] - 2.0f * acc[m][n][r];
                unsigned kb  = __float_as_uint(s);
                unsigned key = kb ^ (unsigned)(((int)kb >> 31) | 0x80000000);
                unsigned col = (unsigned)(k0 + cbase + n * 16 + lrow);
                unsigned long long pk = (((unsigned long long)key) << 32) | col;
                best = pk < best ? pk : best;
            }
            #pragma unroll
            for (int mask = 1; mask <= 8; mask <<= 1) {
                unsigned hi = __shfl_xor((unsigned)(best >> 32), mask, 64);
                unsigned lo = __shfl_xor((unsigned)(best & 0xFFFFFFFFu), mask, 64);
                unsigned long long other = (((unsigned long long)hi) << 32) | lo;
                best = other < best ? other : best;
            }
            if (lrow == 0) {
                int grow = n0 + rbase + m * 16 + lk * 4 + r;
                atomicMin(&packed[grow], best);
            }
        }
    }
}

// ---------------- winner -> class ----------------
__global__ void map_kernel(const unsigned long long* __restrict__ packed,
                           const int* __restrict__ classes,
                           int* __restrict__ out) {
    int n = blockIdx.x * 256 + threadIdx.x;
    if (n < N_ROWS) {
        unsigned col = (unsigned)(packed[n] & 0xFFFFFFFFull);
        out[n] = classes[col];
    }
}

extern "C" void kernel_launch(void* const* d_in, const int* in_sizes, int n_in,
                              void* d_out, int out_size, void* d_ws, size_t ws_size,
                              hipStream_t stream) {
    const float* X       = (const float*)d_in[0];
    const float* C       = (const float*)d_in[1];
    const int*   classes = (const int*)d_in[2];
    int*         out     = (int*)d_out;

    char* ws = (char*)d_ws;
    size_t off = 0;
    unsigned long long* packed = (unsigned long long*)(ws + off); off += (size_t)N_ROWS * 8;
    float* csq = (float*)(ws + off);                              off += (size_t)K_CB * 4;
    unsigned short* Xh = (unsigned short*)(ws + off);             off += (size_t)N_ROWS * DIM * 2;
    unsigned short* Xl = (unsigned short*)(ws + off);             off += (size_t)N_ROWS * DIM * 2;
    unsigned short* Ch = (unsigned short*)(ws + off);             off += (size_t)K_CB * DIM * 2;
    unsigned short* Cl = (unsigned short*)(ws + off);             off += (size_t)K_CB * DIM * 2;

    init_kernel<<<N_ROWS / 256, 256, 0, stream>>>(packed);
    csq_kernel<<<K_CB / 4, 256, 0, stream>>>(C, csq);

    if (ws_size >= off) {
        split_kernel<<<2048, 256, 0, stream>>>(X, Xh, Xl, N_ROWS * DIM / 4);
        split_kernel<<<512, 256, 0, stream>>>(C, Ch, Cl, K_CB * DIM / 4);
        gemm_argmin<<<(N_ROWS / 128) * (K_CB / 128), 256, 0, stream>>>(Xh, Xl, Ch, Cl, csq, packed);
    } else {
        gemm_argmin_fb<<<(N_ROWS / 128) * (K_CB / 128), 256, 0, stream>>>(X, C, csq, packed);
    }
    map_kernel<<<N_ROWS / 256, 256, 0, stream>>>(packed, classes, out);
}

// Round 3
// 261.261 us; speedup vs baseline: 1.7874x; 1.0811x over previous
//
#include <hip/hip_runtime.h>
#include <hip/hip_bf16.h>

// LVQ: out[n] = classes[argmin_k ||x_n - c_k||^2]
// N=65536, D=512, K=1024, classes int32.
//
// score[n][k] = csq[k] - 2 * x_n . c_k   (x_sq dropped: row-constant)
// cross via 3-pass bf16-split MFMA (xh*ch + xh*cl + xl*ch), fp32 accum.
// Round 3: 256x256x32 tiles, 8 waves, double-buffered 128KB dynamic LDS,
// counted vmcnt(8) pipeline (T3+T4), setprio around MFMA clusters (T5),
// source-side XOR swizzle (linear gload_lds dest), 2 sub-phases per K-tile.

#define N_ROWS 65536
#define DIM    512
#define K_CB   1024
#define NT     16          // DIM / BK, BK=32
#define LDSBUF 32768       // elements per buffer: 4 arrays x 8192 (16KB each)

typedef short bf16x8 __attribute__((ext_vector_type(8)));
typedef float f32x4  __attribute__((ext_vector_type(4)));

__device__ __forceinline__ unsigned short f2bf_rn(float f) {
    unsigned u = __float_as_uint(f);
    unsigned r = (u + 0x7FFFu + ((u >> 16) & 1u)) >> 16;
    return (unsigned short)r;
}
__device__ __forceinline__ float bf2f(unsigned short h) {
    return __uint_as_float(((unsigned)h) << 16);
}

__device__ __forceinline__ void gload16(const void* g, void* l) {
    __builtin_amdgcn_global_load_lds(
        (const __attribute__((address_space(1))) unsigned int*)g,
        (__attribute__((address_space(3))) unsigned int*)l, 16, 0, 0);
}

// ---------------- init: packed per-row (min,argmin) to +inf ----------------
__global__ void init_kernel(unsigned long long* __restrict__ packed) {
    int n = blockIdx.x * 256 + threadIdx.x;
    if (n < N_ROWS) packed[n] = ~0ull;
}

// ---------------- csq[k] = sum_d C[k][d]^2 (fp32) ----------------
__global__ void csq_kernel(const float* __restrict__ C, float* __restrict__ csq) {
    int wid  = (blockIdx.x * blockDim.x + threadIdx.x) >> 6;   // one wave per k
    int lane = threadIdx.x & 63;
    const float4* p = (const float4*)(C + (size_t)wid * DIM);
    float4 a = p[lane * 2];
    float4 b = p[lane * 2 + 1];
    float s = a.x*a.x + a.y*a.y + a.z*a.z + a.w*a.w
            + b.x*b.x + b.y*b.y + b.z*b.z + b.w*b.w;
    #pragma unroll
    for (int m = 1; m < 64; m <<= 1) s += __shfl_xor(s, m, 64);
    if (lane == 0) csq[wid] = s;
}

// ---------------- one-shot fp32 -> bf16 hi/lo split ----------------
__global__ void split_kernel(const float* __restrict__ src,
                             unsigned short* __restrict__ h,
                             unsigned short* __restrict__ l, int n4) {
    int stride = gridDim.x * 256;
    for (int i = blockIdx.x * 256 + threadIdx.x; i < n4; i += stride) {
        float4 v = ((const float4*)src)[i];
        ushort4 hh, ll;
        float f;
        f = v.x; hh.x = f2bf_rn(f); ll.x = f2bf_rn(f - bf2f(hh.x));
        f = v.y; hh.y = f2bf_rn(f); ll.y = f2bf_rn(f - bf2f(hh.y));
        f = v.z; hh.z = f2bf_rn(f); ll.z = f2bf_rn(f - bf2f(hh.z));
        f = v.w; hh.w = f2bf_rn(f); ll.w = f2bf_rn(f - bf2f(hh.w));
        ((ushort4*)h)[i] = hh;
        ((ushort4*)l)[i] = ll;
    }
}

// ---------------- fused GEMM + argmin, pipelined ----------------
// LDS tile element layout per array: [row 0..255][group 0..3][8 elems],
// linear idx = row*32 + g*8. Swizzle: LDS[row][g] holds GLOBAL k-group
// g ^ ((row>>1)&3) (applied to the per-lane global source address; LDS
// dest stays linear as global_load_lds requires). Read side uses the same
// XOR; since row bits 1..2 == lrow bits 1..2 for all fragments, the
// swizzle is a single per-lane constant and all 24 frag reads are one
// base + compile-time offsets. 16-lane column reads hit 8 bank-quads
// 2-way (free).
__global__ __launch_bounds__(512, 2)
void gemm_argmin(const unsigned short* __restrict__ Xh,
                 const unsigned short* __restrict__ Xl,
                 const unsigned short* __restrict__ Ch,
                 const unsigned short* __restrict__ Cl,
                 const float* __restrict__ csq,
                 unsigned long long* __restrict__ packed) {
    extern __shared__ unsigned short smem[];   // 2 * LDSBUF elements (128 KB)

    // XCD-aware mapping: the 4 col-tiles of one row-tile run concurrently
    // on one XCD -> X tile (512 KB) fetched into that L2 once.
    int b  = blockIdx.x;
    int x  = b & 7;
    int m8 = b >> 3;                   // 0..127
    int rowtile = x * 32 + (m8 >> 2);  // 0..255
    int coltile = m8 & 3;              // 0..3
    int n0 = rowtile * 256;
    int k0 = coltile * 256;

    int tid  = threadIdx.x;
    int w    = tid >> 6;
    int lane = tid & 63;
    int wr   = w >> 2, wc = w & 3;     // 2M x 4N waves
    int rbase = wr * 128, cbase = wc * 64;
    int lrow = lane & 15;
    int lk   = lane >> 4;              // 0..3
    int sg   = lk ^ ((lrow >> 1) & 3); // per-lane constant swizzled group

    // staging mapping: thread -> (row = c*128 + (tid>>2), group = tid&3)
    int srow = tid >> 2;
    int sgrp = tid & 3;
    int w512 = w * 512;                // wave-uniform part of tid*8

    f32x4 acc[8][4];
    #pragma unroll
    for (int i = 0; i < 8; i++)
        #pragma unroll
        for (int j = 0; j < 4; j++)
            acc[i][j] = (f32x4){0.f, 0.f, 0.f, 0.f};

    // issue all 8 staging chunks for K-tile t into buf[t&1]
    auto issue = [&](int t) {
        int d0 = t * 32;
        unsigned short* buf = smem + (t & 1) * LDSBUF;
        #pragma unroll
        for (int c = 0; c < 2; c++) {
            int r  = c * 128 + srow;
            int gg = sgrp ^ ((r >> 1) & 3);
            size_t oX = (size_t)(n0 + r) * DIM + d0 + gg * 8;
            size_t oC = (size_t)(k0 + r) * DIM + d0 + gg * 8;
            int dl = c * 4096 + w512;             // + lane*8 added by HW
            gload16(Xh + oX, buf + dl);
            gload16(Xl + oX, buf + 8192 + dl);
            gload16(Ch + oC, buf + 16384 + dl);
            gload16(Cl + oC, buf + 24576 + dl);
        }
    };

    issue(0);
    for (int t = 0; t < NT; ++t) {
        if (t + 1 < NT) {
            issue(t + 1);
            // force tile t's 8 chunks complete; keep tile t+1's 8 in flight
            asm volatile("s_waitcnt vmcnt(8)" ::: "memory");
        } else {
            asm volatile("s_waitcnt vmcnt(0)" ::: "memory");
        }
        __builtin_amdgcn_s_barrier();
        asm volatile("" ::: "memory");   // no LDS reads above the barrier

        const unsigned short* buf = smem + (t & 1) * LDSBUF;
        const unsigned short* pA = buf + (rbase + lrow) * 32 + sg * 8;
        const unsigned short* pB = buf + 16384 + (cbase + lrow) * 32 + sg * 8;

        bf16x8 bh[4], bl[4];
        #pragma unroll
        for (int n = 0; n < 4; n++) {
            bh[n] = *(const bf16x8*)(pB + n * 512);
            bl[n] = *(const bf16x8*)(pB + 8192 + n * 512);
        }
        #pragma unroll
        for (int qm = 0; qm < 2; qm++) {
            bf16x8 ah[4], al[4];
            #pragma unroll
            for (int m = 0; m < 4; m++) {
                ah[m] = *(const bf16x8*)(pA + (qm * 4 + m) * 512);
                al[m] = *(const bf16x8*)(pA + 8192 + (qm * 4 + m) * 512);
            }
            __builtin_amdgcn_s_setprio(1);
            #pragma unroll
            for (int m = 0; m < 4; m++)
                #pragma unroll
                for (int n = 0; n < 4; n++) {
                    acc[qm*4+m][n] = __builtin_amdgcn_mfma_f32_16x16x32_bf16(ah[m], bh[n], acc[qm*4+m][n], 0, 0, 0);
                    acc[qm*4+m][n] = __builtin_amdgcn_mfma_f32_16x16x32_bf16(ah[m], bl[n], acc[qm*4+m][n], 0, 0, 0);
                    acc[qm*4+m][n] = __builtin_amdgcn_mfma_f32_16x16x32_bf16(al[m], bh[n], acc[qm*4+m][n], 0, 0, 0);
                }
            __builtin_amdgcn_s_setprio(0);
            if (qm == 0) __builtin_amdgcn_s_barrier();   // wave alignment
        }
        asm volatile("" ::: "memory");   // no LDS reads below end barrier
        __builtin_amdgcn_s_barrier();    // buf[t&1] free for tile t+2 issue
    }

    // Epilogue: score = csq[col] - 2*cross; per-row packed-min, atomic merge.
    float cs[4];
    #pragma unroll
    for (int n = 0; n < 4; n++) cs[n] = csq[k0 + cbase + n * 16 + lrow];

    #pragma unroll
    for (int m = 0; m < 8; m++) {
        #pragma unroll
        for (int r = 0; r < 4; r++) {
            unsigned long long best = ~0ull;
            #pragma unroll
            for (int n = 0; n < 4; n++) {
                float s = cs[n] - 2.0f * acc[m][n][r];
                unsigned kb  = __float_as_uint(s);
                unsigned key = kb ^ (unsigned)(((int)kb >> 31) | 0x80000000);
                unsigned col = (unsigned)(k0 + cbase + n * 16 + lrow);
                unsigned long long pk = (((unsigned long long)key) << 32) | col;
                best = pk < best ? pk : best;
            }
            #pragma unroll
            for (int mask = 1; mask <= 8; mask <<= 1) {
                unsigned hi = __shfl_xor((unsigned)(best >> 32), mask, 64);
                unsigned lo = __shfl_xor((unsigned)(best & 0xFFFFFFFFu), mask, 64);
                unsigned long long other = (((unsigned long long)hi) << 32) | lo;
                best = other < best ? other : best;
            }
            if (lrow == 0) {
                int grow = n0 + rbase + m * 16 + lk * 4 + r;
                atomicMin(&packed[grow], best);
            }
        }
    }
}

// ---------------- fallback GEMM (in-kernel conversion, round-1 path) -------
__device__ __forceinline__ void stage_tile_fb(const float* __restrict__ src,
                                              unsigned short* __restrict__ Hh,
                                              unsigned short* __restrict__ Hl,
                                              int t) {
    int rsub = t >> 4;
    int f4i  = t & 15;
    int g    = f4i >> 1;
    int off  = (f4i & 1) * 4;
    #pragma unroll
    for (int p = 0; p < 8; p++) {
        int row = p * 16 + rsub;
        float4 v = *(const float4*)(src + (size_t)row * DIM + f4i * 4);
        ushort4 h, l;
        float f;
        f = v.x; h.x = f2bf_rn(f); l.x = f2bf_rn(f - bf2f(h.x));
        f = v.y; h.y = f2bf_rn(f); l.y = f2bf_rn(f - bf2f(h.y));
        f = v.z; h.z = f2bf_rn(f); l.z = f2bf_rn(f - bf2f(h.z));
        f = v.w; h.w = f2bf_rn(f); l.w = f2bf_rn(f - bf2f(h.w));
        int sg  = g ^ (row & 7);
        int idx = row * 64 + sg * 8 + off;
        *(ushort4*)(Hh + idx) = h;
        *(ushort4*)(Hl + idx) = l;
    }
}

__global__ __launch_bounds__(256, 2)
void gemm_argmin_fb(const float* __restrict__ X, const float* __restrict__ C,
                    const float* __restrict__ csq,
                    unsigned long long* __restrict__ packed) {
    __shared__ unsigned short AhL[128 * 64];
    __shared__ unsigned short AlL[128 * 64];
    __shared__ unsigned short BhL[128 * 64];
    __shared__ unsigned short BlL[128 * 64];

    int b = blockIdx.x;
    int x = b & 7;
    int m8 = b >> 3;
    int rowtile = x * 64 + (m8 >> 3);
    int coltile = m8 & 7;
    int n0 = rowtile * 128;
    int k0 = coltile * 128;

    int t    = threadIdx.x;
    int w    = t >> 6;
    int lane = t & 63;
    int wr   = w >> 1, wc = w & 1;
    int rbase = wr * 64, cbase = wc * 64;
    int lrow = lane & 15;
    int lk   = lane >> 4;

    f32x4 acc[4][4];
    #pragma unroll
    for (int i = 0; i < 4; i++)
        #pragma unroll
        for (int j = 0; j < 4; j++)
            acc[i][j] = (f32x4){0.f, 0.f, 0.f, 0.f};

    for (int d0 = 0; d0 < DIM; d0 += 64) {
        stage_tile_fb(X + (size_t)n0 * DIM + d0, AhL, AlL, t);
        stage_tile_fb(C + (size_t)k0 * DIM + d0, BhL, BlL, t);
        __syncthreads();

        #pragma unroll
        for (int kk = 0; kk < 2; kk++) {
            int gidx = kk * 4 + lk;
            bf16x8 ah[4], al[4], bh[4], bl[4];
            #pragma unroll
            for (int m = 0; m < 4; m++) {
                int row = rbase + m * 16 + lrow;
                int sg  = gidx ^ (row & 7);
                ah[m] = *(const bf16x8*)&AhL[row * 64 + sg * 8];
                al[m] = *(const bf16x8*)&AlL[row * 64 + sg * 8];
            }
            #pragma unroll
            for (int n = 0; n < 4; n++) {
                int col = cbase + n * 16 + lrow;
                int sg  = gidx ^ (col & 7);
                bh[n] = *(const bf16x8*)&BhL[col * 64 + sg * 8];
                bl[n] = *(const bf16x8*)&BlL[col * 64 + sg * 8];
            }
            #pragma unroll
            for (int m = 0; m < 4; m++)
                #pragma unroll
                for (int n = 0; n < 4; n++) {
                    acc[m][n] = __builtin_amdgcn_mfma_f32_16x16x32_bf16(ah[m], bh[n], acc[m][n], 0, 0, 0);
                    acc[m][n] = __builtin_amdgcn_mfma_f32_16x16x32_bf16(ah[m], bl[n], acc[m][n], 0, 0, 0);
                    acc[m][n] = __builtin_amdgcn_mfma_f32_16x16x32_bf16(al[m], bh[n], acc[m][n], 0, 0, 0);
                }
        }
        __syncthreads();
    }

    float cs[4];
    #pragma unroll
    for (int n = 0; n < 4; n++) cs[n] = csq[k0 + cbase + n * 16 + lrow];

    #pragma unroll
    for (int m = 0; m < 4; m++) {
        #pragma unroll
        for (int r = 0; r < 4; r++) {
            unsigned long long best = ~0ull;
            #pragma unroll
            for (int n = 0; n < 4; n++) {
                float s = cs[n] - 2.0f * acc[m][n][r];
                unsigned kb  = __float_as_uint(s);
                unsigned key = kb ^ (unsigned)(((int)kb >> 31) | 0x80000000);
                unsigned col = (unsigned)(k0 + cbase + n * 16 + lrow);
                unsigned long long pk = (((unsigned long long)key) << 32) | col;
                best = pk < best ? pk : best;
            }
            #pragma unroll
            for (int mask = 1; mask <= 8; mask <<= 1) {
                unsigned hi = __shfl_xor((unsigned)(best >> 32), mask, 64);
                unsigned lo = __shfl_xor((unsigned)(best & 0xFFFFFFFFu), mask, 64);
                unsigned long long other = (((unsigned long long)hi) << 32) | lo;
                best = other < best ? other : best;
            }
            if (lrow == 0) {
                int grow = n0 + rbase + m * 16 + lk * 4 + r;
                atomicMin(&packed[grow], best);
            }
        }
    }
}

// ---------------- winner -> class ----------------
__global__ void map_kernel(const unsigned long long* __restrict__ packed,
                           const int* __restrict__ classes,
                           int* __restrict__ out) {
    int n = blockIdx.x * 256 + threadIdx.x;
    if (n < N_ROWS) {
        unsigned col = (unsigned)(packed[n] & 0xFFFFFFFFull);
        out[n] = classes[col];
    }
}

extern "C" void kernel_launch(void* const* d_in, const int* in_sizes, int n_in,
                              void* d_out, int out_size, void* d_ws, size_t ws_size,
                              hipStream_t stream) {
    const float* X       = (const float*)d_in[0];
    const float* C       = (const float*)d_in[1];
    const int*   classes = (const int*)d_in[2];
    int*         out     = (int*)d_out;

    char* ws = (char*)d_ws;
    size_t off = 0;
    unsigned long long* packed = (unsigned long long*)(ws + off); off += (size_t)N_ROWS * 8;
    float* csq = (float*)(ws + off);                              off += (size_t)K_CB * 4;
    unsigned short* Xh = (unsigned short*)(ws + off);             off += (size_t)N_ROWS * DIM * 2;
    unsigned short* Xl = (unsigned short*)(ws + off);             off += (size_t)N_ROWS * DIM * 2;
    unsigned short* Ch = (unsigned short*)(ws + off);             off += (size_t)K_CB * DIM * 2;
    unsigned short* Cl = (unsigned short*)(ws + off);             off += (size_t)K_CB * DIM * 2;

    init_kernel<<<N_ROWS / 256, 256, 0, stream>>>(packed);
    csq_kernel<<<K_CB / 4, 256, 0, stream>>>(C, csq);

    if (ws_size >= off) {
        split_kernel<<<2048, 256, 0, stream>>>(X, Xh, Xl, N_ROWS * DIM / 4);
        split_kernel<<<512, 256, 0, stream>>>(C, Ch, Cl, K_CB * DIM / 4);
        // 128 KB dynamic LDS: set attr on the (uncaptured) correctness call;
        // persists for the captured/replayed launches.
        hipFuncSetAttribute((const void*)gemm_argmin,
                            hipFuncAttributeMaxDynamicSharedMemorySize,
                            2 * LDSBUF * sizeof(unsigned short));
        gemm_argmin<<<(N_ROWS / 256) * (K_CB / 256), 512,
                      2 * LDSBUF * sizeof(unsigned short), stream>>>(
            Xh, Xl, Ch, Cl, csq, packed);
    } else {
        gemm_argmin_fb<<<(N_ROWS / 128) * (K_CB / 128), 256, 0, stream>>>(X, C, csq, packed);
    }
    map_kernel<<<N_ROWS / 256, 256, 0, stream>>>(packed, classes, out);
}

// Round 4
// 254.716 us; speedup vs baseline: 1.8333x; 1.0257x over previous
//
#include <hip/hip_runtime.h>
#include <hip/hip_bf16.h>

// LVQ: out[n] = classes[argmin_k ||x_n - c_k||^2]
// N=65536, D=512, K=1024, classes int32.
//
// score[n][k] = csq[k] - 2 * x_n . c_k   (x_sq dropped: row-constant)
// cross via 3-pass bf16-split MFMA (xh*ch + xh*cl + xl*ch), fp32 accum.
// Round 4: fine-phase schedule. 256x256x32 tiles, 8 waves, 128KB dbuf LDS.
// Per K-tile: 4 phases, each {4 A ds_reads, gload issues, barrier, setprio,
// 24 pass-major MFMA}. Pass-major order = 8 independent MFMAs between
// dependent accumulator reuses (kills MFMA dep stalls at 2 waves/SIMD).
// vmcnt(0) once per tile at phase 3 (loads issued 2-3 phases earlier).

#define N_ROWS 65536
#define DIM    512
#define K_CB   1024
#define NT     16          // DIM / BK, BK=32
#define LDSBUF 32768       // elements per buffer: 4 arrays x 8192 (16KB each)

typedef short bf16x8 __attribute__((ext_vector_type(8)));
typedef float f32x4  __attribute__((ext_vector_type(4)));

__device__ __forceinline__ unsigned short f2bf_rn(float f) {
    unsigned u = __float_as_uint(f);
    unsigned r = (u + 0x7FFFu + ((u >> 16) & 1u)) >> 16;
    return (unsigned short)r;
}
__device__ __forceinline__ float bf2f(unsigned short h) {
    return __uint_as_float(((unsigned)h) << 16);
}

__device__ __forceinline__ void gload16(const void* g, void* l) {
    __builtin_amdgcn_global_load_lds(
        (const __attribute__((address_space(1))) unsigned int*)g,
        (__attribute__((address_space(3))) unsigned int*)l, 16, 0, 0);
}

// ---------------- init: packed per-row (min,argmin) to +inf ----------------
__global__ void init_kernel(unsigned long long* __restrict__ packed) {
    int n = blockIdx.x * 256 + threadIdx.x;
    if (n < N_ROWS) packed[n] = ~0ull;
}

// ---------------- csq[k] = sum_d C[k][d]^2 (fp32) ----------------
__global__ void csq_kernel(const float* __restrict__ C, float* __restrict__ csq) {
    int wid  = (blockIdx.x * blockDim.x + threadIdx.x) >> 6;   // one wave per k
    int lane = threadIdx.x & 63;
    const float4* p = (const float4*)(C + (size_t)wid * DIM);
    float4 a = p[lane * 2];
    float4 b = p[lane * 2 + 1];
    float s = a.x*a.x + a.y*a.y + a.z*a.z + a.w*a.w
            + b.x*b.x + b.y*b.y + b.z*b.z + b.w*b.w;
    #pragma unroll
    for (int m = 1; m < 64; m <<= 1) s += __shfl_xor(s, m, 64);
    if (lane == 0) csq[wid] = s;
}

// ---------------- one-shot fp32 -> bf16 hi/lo split ----------------
__global__ void split_kernel(const float* __restrict__ src,
                             unsigned short* __restrict__ h,
                             unsigned short* __restrict__ l, int n4) {
    int stride = gridDim.x * 256;
    for (int i = blockIdx.x * 256 + threadIdx.x; i < n4; i += stride) {
        float4 v = ((const float4*)src)[i];
        ushort4 hh, ll;
        float f;
        f = v.x; hh.x = f2bf_rn(f); ll.x = f2bf_rn(f - bf2f(hh.x));
        f = v.y; hh.y = f2bf_rn(f); ll.y = f2bf_rn(f - bf2f(hh.y));
        f = v.z; hh.z = f2bf_rn(f); ll.z = f2bf_rn(f - bf2f(hh.z));
        f = v.w; hh.w = f2bf_rn(f); ll.w = f2bf_rn(f - bf2f(hh.w));
        ((ushort4*)h)[i] = hh;
        ((ushort4*)l)[i] = ll;
    }
}

// ---------------- fused GEMM + argmin, fine-phase pipeline ----------------
// LDS tile element layout per array: [row 0..255][group 0..3][8 elems],
// linear idx = row*32 + g*8. LDS[row][g] holds GLOBAL k-group g^((row>>1)&3)
// (swizzle applied on the per-lane global source address; linear LDS dest as
// global_load_lds requires). Reads use the same XOR; wave64 b128 reads hit
// the 8-phase LDS minimum (0 conflicts, measured r2/r3).
__global__ __launch_bounds__(512, 2)
void gemm_argmin(const unsigned short* __restrict__ Xh,
                 const unsigned short* __restrict__ Xl,
                 const unsigned short* __restrict__ Ch,
                 const unsigned short* __restrict__ Cl,
                 const float* __restrict__ csq,
                 unsigned long long* __restrict__ packed) {
    extern __shared__ unsigned short smem[];   // 2 * LDSBUF elements (128 KB)

    // XCD-aware mapping: the 4 col-tiles of one row-tile run concurrently
    // on one XCD -> X tile (512 KB) fetched into that L2 once.
    int b  = blockIdx.x;
    int x  = b & 7;
    int m8 = b >> 3;                   // 0..127
    int rowtile = x * 32 + (m8 >> 2);  // 0..255
    int coltile = m8 & 3;              // 0..3
    int n0 = rowtile * 256;
    int k0 = coltile * 256;

    int tid  = threadIdx.x;
    int w    = tid >> 6;
    int lane = tid & 63;
    int wr   = w >> 2, wc = w & 3;     // 2M x 4N waves
    int rbase = wr * 128, cbase = wc * 64;
    int lrow = lane & 15;
    int lk   = lane >> 4;              // 0..3
    int sg   = lk ^ ((lrow >> 1) & 3); // per-lane constant swizzled group

    // staging mapping: thread -> (row = c*128 + (tid>>2), group = tid&3)
    int srow = tid >> 2;
    int sgrp = tid & 3;
    int w512 = w * 512;                // wave-uniform part of tid*8

    f32x4 acc[8][4];
    #pragma unroll
    for (int i = 0; i < 8; i++)
        #pragma unroll
        for (int j = 0; j < 4; j++)
            acc[i][j] = (f32x4){0.f, 0.f, 0.f, 0.f};

    // issue 4 staging chunks (half c) for K-tile t into buf[t&1]
    auto issue_half = [&](int t, int c) {
        int d0 = t * 32;
        unsigned short* bufn = smem + (t & 1) * LDSBUF;
        int r  = c * 128 + srow;
        int gg = sgrp ^ ((r >> 1) & 3);
        size_t oX = (size_t)(n0 + r) * DIM + d0 + gg * 8;
        size_t oC = (size_t)(k0 + r) * DIM + d0 + gg * 8;
        int dl = c * 4096 + w512;             // + lane*8 added by HW
        gload16(Xh + oX, bufn + dl);
        gload16(Xl + oX, bufn + 8192 + dl);
        gload16(Ch + oC, bufn + 16384 + dl);
        gload16(Cl + oC, bufn + 24576 + dl);
    };

    issue_half(0, 0);
    issue_half(0, 1);
    asm volatile("s_waitcnt vmcnt(0)" ::: "memory");
    __builtin_amdgcn_s_barrier();

    for (int t = 0; t < NT; ++t) {
        const unsigned short* buf = smem + (t & 1) * LDSBUF;
        const unsigned short* pA = buf + (rbase + lrow) * 32 + sg * 8;
        const unsigned short* pB = buf + 16384 + (cbase + lrow) * 32 + sg * 8;

        // B fragments for the whole K-tile (8 reads), held in regs.
        bf16x8 bh[4], bl[4];
        #pragma unroll
        for (int n = 0; n < 4; n++) {
            bh[n] = *(const bf16x8*)(pB + n * 512);
            bl[n] = *(const bf16x8*)(pB + 8192 + n * 512);
        }

        #pragma unroll
        for (int p = 0; p < 4; p++) {
            // A fragments for this phase (4 reads), issued pre-barrier so
            // latency hides under the barrier wait.
            bf16x8 ah[2], al[2];
            #pragma unroll
            for (int mm = 0; mm < 2; mm++) {
                ah[mm] = *(const bf16x8*)(pA + (2*p + mm) * 512);
                al[mm] = *(const bf16x8*)(pA + 8192 + (2*p + mm) * 512);
            }
            if (p == 0 && t + 1 < NT) issue_half(t + 1, 0);
            if (p == 1 && t + 1 < NT) issue_half(t + 1, 1);
            if (p == 3)   // tile t+1's 8 gloads (issued 2-3 phases ago) landed
                asm volatile("s_waitcnt vmcnt(0)" ::: "memory");
            __builtin_amdgcn_s_barrier();

            __builtin_amdgcn_s_setprio(1);
            // pass-major: 8 independent MFMAs between dependent acc reuses;
            // per-acc contribution order (hh, hl, lh) identical to r2/r3.
            #pragma unroll
            for (int mm = 0; mm < 2; mm++)
                #pragma unroll
                for (int n = 0; n < 4; n++)
                    acc[2*p+mm][n] = __builtin_amdgcn_mfma_f32_16x16x32_bf16(ah[mm], bh[n], acc[2*p+mm][n], 0, 0, 0);
            #pragma unroll
            for (int mm = 0; mm < 2; mm++)
                #pragma unroll
                for (int n = 0; n < 4; n++)
                    acc[2*p+mm][n] = __builtin_amdgcn_mfma_f32_16x16x32_bf16(ah[mm], bl[n], acc[2*p+mm][n], 0, 0, 0);
            #pragma unroll
            for (int mm = 0; mm < 2; mm++)
                #pragma unroll
                for (int n = 0; n < 4; n++)
                    acc[2*p+mm][n] = __builtin_amdgcn_mfma_f32_16x16x32_bf16(al[mm], bh[n], acc[2*p+mm][n], 0, 0, 0);
            __builtin_amdgcn_s_setprio(0);
        }
        // boundary: all waves' phase-3 MFMAs done => all ds_reads of buf[t&1]
        // consumed => safe to overwrite (gloads issued next tile) and
        // buf[(t+1)&1] (vmcnt(0)'d above) safe to read.
        __builtin_amdgcn_s_barrier();
    }

    // Epilogue: score = csq[col] - 2*cross; per-row packed-min, atomic merge.
    float cs[4];
    #pragma unroll
    for (int n = 0; n < 4; n++) cs[n] = csq[k0 + cbase + n * 16 + lrow];

    #pragma unroll
    for (int m = 0; m < 8; m++) {
        #pragma unroll
        for (int r = 0; r < 4; r++) {
            unsigned long long best = ~0ull;
            #pragma unroll
            for (int n = 0; n < 4; n++) {
                float s = cs[n] - 2.0f * acc[m][n][r];
                unsigned kb  = __float_as_uint(s);
                unsigned key = kb ^ (unsigned)(((int)kb >> 31) | 0x80000000);
                unsigned col = (unsigned)(k0 + cbase + n * 16 + lrow);
                unsigned long long pk = (((unsigned long long)key) << 32) | col;
                best = pk < best ? pk : best;
            }
            #pragma unroll
            for (int mask = 1; mask <= 8; mask <<= 1) {
                unsigned hi = __shfl_xor((unsigned)(best >> 32), mask, 64);
                unsigned lo = __shfl_xor((unsigned)(best & 0xFFFFFFFFu), mask, 64);
                unsigned long long other = (((unsigned long long)hi) << 32) | lo;
                best = other < best ? other : best;
            }
            if (lrow == 0) {
                int grow = n0 + rbase + m * 16 + lk * 4 + r;
                atomicMin(&packed[grow], best);
            }
        }
    }
}

// ---------------- fallback GEMM (in-kernel conversion, round-1 path) -------
__device__ __forceinline__ void stage_tile_fb(const float* __restrict__ src,
                                              unsigned short* __restrict__ Hh,
                                              unsigned short* __restrict__ Hl,
                                              int t) {
    int rsub = t >> 4;
    int f4i  = t & 15;
    int g    = f4i >> 1;
    int off  = (f4i & 1) * 4;
    #pragma unroll
    for (int p = 0; p < 8; p++) {
        int row = p * 16 + rsub;
        float4 v = *(const float4*)(src + (size_t)row * DIM + f4i * 4);
        ushort4 h, l;
        float f;
        f = v.x; h.x = f2bf_rn(f); l.x = f2bf_rn(f - bf2f(h.x));
        f = v.y; h.y = f2bf_rn(f); l.y = f2bf_rn(f - bf2f(h.y));
        f = v.z; h.z = f2bf_rn(f); l.z = f2bf_rn(f - bf2f(h.z));
        f = v.w; h.w = f2bf_rn(f); l.w = f2bf_rn(f - bf2f(h.w));
        int sg  = g ^ (row & 7);
        int idx = row * 64 + sg * 8 + off;
        *(ushort4*)(Hh + idx) = h;
        *(ushort4*)(Hl + idx) = l;
    }
}

__global__ __launch_bounds__(256, 2)
void gemm_argmin_fb(const float* __restrict__ X, const float* __restrict__ C,
                    const float* __restrict__ csq,
                    unsigned long long* __restrict__ packed) {
    __shared__ unsigned short AhL[128 * 64];
    __shared__ unsigned short AlL[128 * 64];
    __shared__ unsigned short BhL[128 * 64];
    __shared__ unsigned short BlL[128 * 64];

    int b = blockIdx.x;
    int x = b & 7;
    int m8 = b >> 3;
    int rowtile = x * 64 + (m8 >> 3);
    int coltile = m8 & 7;
    int n0 = rowtile * 128;
    int k0 = coltile * 128;

    int t    = threadIdx.x;
    int w    = t >> 6;
    int lane = t & 63;
    int wr   = w >> 1, wc = w & 1;
    int rbase = wr * 64, cbase = wc * 64;
    int lrow = lane & 15;
    int lk   = lane >> 4;

    f32x4 acc[4][4];
    #pragma unroll
    for (int i = 0; i < 4; i++)
        #pragma unroll
        for (int j = 0; j < 4; j++)
            acc[i][j] = (f32x4){0.f, 0.f, 0.f, 0.f};

    for (int d0 = 0; d0 < DIM; d0 += 64) {
        stage_tile_fb(X + (size_t)n0 * DIM + d0, AhL, AlL, t);
        stage_tile_fb(C + (size_t)k0 * DIM + d0, BhL, BlL, t);
        __syncthreads();

        #pragma unroll
        for (int kk = 0; kk < 2; kk++) {
            int gidx = kk * 4 + lk;
            bf16x8 ah[4], al[4], bh[4], bl[4];
            #pragma unroll
            for (int m = 0; m < 4; m++) {
                int row = rbase + m * 16 + lrow;
                int sg  = gidx ^ (row & 7);
                ah[m] = *(const bf16x8*)&AhL[row * 64 + sg * 8];
                al[m] = *(const bf16x8*)&AlL[row * 64 + sg * 8];
            }
            #pragma unroll
            for (int n = 0; n < 4; n++) {
                int col = cbase + n * 16 + lrow;
                int sg  = gidx ^ (col & 7);
                bh[n] = *(const bf16x8*)&BhL[col * 64 + sg * 8];
                bl[n] = *(const bf16x8*)&BlL[col * 64 + sg * 8];
            }
            #pragma unroll
            for (int m = 0; m < 4; m++)
                #pragma unroll
                for (int n = 0; n < 4; n++) {
                    acc[m][n] = __builtin_amdgcn_mfma_f32_16x16x32_bf16(ah[m], bh[n], acc[m][n], 0, 0, 0);
                    acc[m][n] = __builtin_amdgcn_mfma_f32_16x16x32_bf16(ah[m], bl[n], acc[m][n], 0, 0, 0);
                    acc[m][n] = __builtin_amdgcn_mfma_f32_16x16x32_bf16(al[m], bh[n], acc[m][n], 0, 0, 0);
                }
        }
        __syncthreads();
    }

    float cs[4];
    #pragma unroll
    for (int n = 0; n < 4; n++) cs[n] = csq[k0 + cbase + n * 16 + lrow];

    #pragma unroll
    for (int m = 0; m < 4; m++) {
        #pragma unroll
        for (int r = 0; r < 4; r++) {
            unsigned long long best = ~0ull;
            #pragma unroll
            for (int n = 0; n < 4; n++) {
                float s = cs[n] - 2.0f * acc[m][n][r];
                unsigned kb  = __float_as_uint(s);
                unsigned key = kb ^ (unsigned)(((int)kb >> 31) | 0x80000000);
                unsigned col = (unsigned)(k0 + cbase + n * 16 + lrow);
                unsigned long long pk = (((unsigned long long)key) << 32) | col;
                best = pk < best ? pk : best;
            }
            #pragma unroll
            for (int mask = 1; mask <= 8; mask <<= 1) {
                unsigned hi = __shfl_xor((unsigned)(best >> 32), mask, 64);
                unsigned lo = __shfl_xor((unsigned)(best & 0xFFFFFFFFu), mask, 64);
                unsigned long long other = (((unsigned long long)hi) << 32) | lo;
                best = other < best ? other : best;
            }
            if (lrow == 0) {
                int grow = n0 + rbase + m * 16 + lk * 4 + r;
                atomicMin(&packed[grow], best);
            }
        }
    }
}

// ---------------- winner -> class ----------------
__global__ void map_kernel(const unsigned long long* __restrict__ packed,
                           const int* __restrict__ classes,
                           int* __restrict__ out) {
    int n = blockIdx.x * 256 + threadIdx.x;
    if (n < N_ROWS) {
        unsigned col = (unsigned)(packed[n] & 0xFFFFFFFFull);
        out[n] = classes[col];
    }
}

extern "C" void kernel_launch(void* const* d_in, const int* in_sizes, int n_in,
                              void* d_out, int out_size, void* d_ws, size_t ws_size,
                              hipStream_t stream) {
    const float* X       = (const float*)d_in[0];
    const float* C       = (const float*)d_in[1];
    const int*   classes = (const int*)d_in[2];
    int*         out     = (int*)d_out;

    char* ws = (char*)d_ws;
    size_t off = 0;
    unsigned long long* packed = (unsigned long long*)(ws + off); off += (size_t)N_ROWS * 8;
    float* csq = (float*)(ws + off);                              off += (size_t)K_CB * 4;
    unsigned short* Xh = (unsigned short*)(ws + off);             off += (size_t)N_ROWS * DIM * 2;
    unsigned short* Xl = (unsigned short*)(ws + off);             off += (size_t)N_ROWS * DIM * 2;
    unsigned short* Ch = (unsigned short*)(ws + off);             off += (size_t)K_CB * DIM * 2;
    unsigned short* Cl = (unsigned short*)(ws + off);             off += (size_t)K_CB * DIM * 2;

    init_kernel<<<N_ROWS / 256, 256, 0, stream>>>(packed);
    csq_kernel<<<K_CB / 4, 256, 0, stream>>>(C, csq);

    if (ws_size >= off) {
        split_kernel<<<2048, 256, 0, stream>>>(X, Xh, Xl, N_ROWS * DIM / 4);
        split_kernel<<<512, 256, 0, stream>>>(C, Ch, Cl, K_CB * DIM / 4);
        hipFuncSetAttribute((const void*)gemm_argmin,
                            hipFuncAttributeMaxDynamicSharedMemorySize,
                            2 * LDSBUF * sizeof(unsigned short));
        gemm_argmin<<<(N_ROWS / 256) * (K_CB / 256), 512,
                      2 * LDSBUF * sizeof(unsigned short), stream>>>(
            Xh, Xl, Ch, Cl, csq, packed);
    } else {
        gemm_argmin_fb<<<(N_ROWS / 128) * (K_CB / 128), 256, 0, stream>>>(X, C, csq, packed);
    }
    map_kernel<<<N_ROWS / 256, 256, 0, stream>>>(packed, classes, out);
}